// Round 1
// baseline (975.817 us; speedup 1.0000x reference)
//
#include <hip/hip_runtime.h>

#define B_ 16
#define T_ 4096
#define D_ 768
#define NBOX 1024
#define MAXBB 128
#define DDETR 256

// ---------------- mean over T (two-stage, deterministic) ----------------
// grid: B_*64 blocks, 256 threads. Each block sums 64 t-rows of one batch.
__global__ void k_mean_partial(const float* __restrict__ in, float* __restrict__ part) {
    int blk = blockIdx.x;
    int b = blk >> 6;   // /64
    int c = blk & 63;
    int tid = threadIdx.x;
    float s0 = 0.f, s1 = 0.f, s2 = 0.f;
    const float* base = in + (size_t)b * T_ * D_ + (size_t)c * 64 * D_;
    for (int t = 0; t < 64; ++t) {
        const float* p = base + (size_t)t * D_;
        s0 += p[tid];
        s1 += p[tid + 256];
        s2 += p[tid + 512];
    }
    float* o = part + (size_t)blk * D_;
    o[tid] = s0; o[tid + 256] = s1; o[tid + 512] = s2;
}

__global__ void k_mean_final(const float* __restrict__ part, float* __restrict__ x) {
    int idx = blockIdx.x * blockDim.x + threadIdx.x;
    if (idx >= B_ * D_) return;
    int b = idx / D_;
    int d = idx - b * D_;
    float s = 0.f;
    for (int c = 0; c < 64; ++c) s += part[(size_t)(b * 64 + c) * D_ + d];
    x[idx] = s * (1.0f / T_);
}

// ---------------- generic tiled GEMM: C = act(A @ W^T + bias) ----------------
// A: (M,K) lda, W: (N,K) ldw, C: (M,N) ldc. 32x32x32 tiles, 256 threads,
// 4 outputs/thread (rows ty, ty+8, ty+16, ty+24 at col tx).
template<int RELU>
__global__ void k_gemm_wt(const float* __restrict__ A, int lda,
                          const float* __restrict__ W, int ldw,
                          const float* __restrict__ bias,
                          float* __restrict__ C, int ldc,
                          int M, int N, int K) {
    __shared__ float As[32][33];
    __shared__ float Ws[32][33];
    int tid = threadIdx.x;
    int tx = tid & 31;
    int ty = tid >> 5;
    int m0 = blockIdx.y * 32;
    int n0 = blockIdx.x * 32;
    float acc[4] = {0.f, 0.f, 0.f, 0.f};
    for (int k0 = 0; k0 < K; k0 += 32) {
        #pragma unroll
        for (int i = 0; i < 4; ++i) {
            int lin = tid + i * 256;
            int r = lin >> 5, cc = lin & 31;
            int m = m0 + r, k = k0 + cc;
            As[r][cc] = (m < M && k < K) ? A[(size_t)m * lda + k] : 0.f;
            int n = n0 + r;
            Ws[r][cc] = (n < N && k < K) ? W[(size_t)n * ldw + k] : 0.f;
        }
        __syncthreads();
        #pragma unroll
        for (int kk = 0; kk < 32; ++kk) {
            float wv = Ws[tx][kk];
            acc[0] += As[ty][kk] * wv;
            acc[1] += As[ty + 8][kk] * wv;
            acc[2] += As[ty + 16][kk] * wv;
            acc[3] += As[ty + 24][kk] * wv;
        }
        __syncthreads();
    }
    int n = n0 + tx;
    if (n < N) {
        float bv = bias ? bias[n] : 0.f;
        #pragma unroll
        for (int i = 0; i < 4; ++i) {
            int m = m0 + ty + i * 8;
            if (m < M) {
                float v = acc[i] + bv;
                if (RELU) v = v > 0.f ? v : 0.f;
                C[(size_t)m * ldc + n] = v;
            }
        }
    }
}

// ---------------- gather xt[img[i]] into left half of concat buffer ----------------
__global__ void k_gather_xt(const float* __restrict__ xt, const int* __restrict__ bboxes,
                            float* __restrict__ hxcat) {
    int i = blockIdx.x;
    int img = bboxes[i * 5];
    const float* src = xt + (size_t)img * D_;
    float* dst = hxcat + (size_t)i * (2 * D_);
    for (int d = threadIdx.x; d < D_; d += blockDim.x) dst[d] = src[d];
}

// ---------------- counts / offsets / pos / att_mask ----------------
__global__ void k_meta(const int* __restrict__ bboxes, int* __restrict__ pos,
                       float* __restrict__ att_mask) {
    __shared__ int cnt[B_];
    __shared__ int off[B_];
    int tid = threadIdx.x;
    if (tid < B_) cnt[tid] = 0;
    __syncthreads();
    for (int i = tid; i < NBOX; i += blockDim.x) atomicAdd(&cnt[bboxes[i * 5]], 1);
    __syncthreads();
    if (tid == 0) {
        int acc = 0;
        for (int b = 0; b < B_; ++b) { off[b] = acc; acc += cnt[b]; }
    }
    __syncthreads();
    for (int i = tid; i < NBOX; i += blockDim.x) pos[i] = i - off[bboxes[i * 5]];
    for (int j = tid; j < B_ * MAXBB; j += blockDim.x) {
        int b = j / MAXBB, p = j - b * MAXBB;
        att_mask[j] = (p < cnt[b]) ? 1.0f : 0.0f;
    }
}

// ---------------- scatter h rows into vis_output ----------------
__global__ void k_scatter(const float* __restrict__ h, const int* __restrict__ bboxes,
                          const int* __restrict__ pos, float* __restrict__ vis) {
    int i = blockIdx.x;
    int b = bboxes[i * 5];
    int p = pos[i];
    if (p < 0 || p >= MAXBB) return;  // JAX drops OOB scatters
    float* dst = vis + ((size_t)b * MAXBB + p) * D_;
    const float* src = h + (size_t)i * D_;
    for (int d = threadIdx.x; d < D_; d += blockDim.x) dst[d] = src[d];
}

__global__ void k_zero(float* __restrict__ p, int n) {
    int i = blockIdx.x * blockDim.x + threadIdx.x;
    if (i < n) p[i] = 0.f;
}

extern "C" void kernel_launch(void* const* d_in, const int* in_sizes, int n_in,
                              void* d_out, int out_size, void* d_ws, size_t ws_size,
                              hipStream_t stream) {
    const float* inputs   = (const float*)d_in[0];
    const int*   bboxes   = (const int*)d_in[1];
    const float* features = (const float*)d_in[2];
    const float* t1w = (const float*)d_in[3];
    const float* t1b = (const float*)d_in[4];
    const float* t2w = (const float*)d_in[5];
    const float* t2b = (const float*)d_in[6];
    const float* d1w = (const float*)d_in[7];
    const float* d1b = (const float*)d_in[8];
    const float* d2w = (const float*)d_in[9];
    const float* d2b = (const float*)d_in[10];
    const float* m1w = (const float*)d_in[11];
    const float* m1b = (const float*)d_in[12];
    const float* m2w = (const float*)d_in[13];
    const float* m2b = (const float*)d_in[14];
    const float* pw  = (const float*)d_in[15];
    const float* pb  = (const float*)d_in[16];

    float* out  = (float*)d_out;
    float* vis  = out;                       // 16*128*768 = 1572864
    float* att  = out + 1572864;             // 16*128     = 2048
    float* retx = out + 1574912;             // 16*768     = 12288

    float* ws    = (float*)d_ws;
    float* part  = ws;                        // 1024*768 = 786432
    float* x     = part + 786432;             // 12288
    float* h1d   = x + 12288;                 // 12288
    float* h1t   = h1d + 12288;               // 12288
    float* xt    = h1t + 12288;               // 12288
    float* fm1   = xt + 12288;                // 786432
    float* hxcat = fm1 + 786432;              // 1024*1536 = 1572864
    float* h     = hxcat + 1572864;           // 786432
    int*   pos   = (int*)(h + 786432);        // 1024 ints

    // zero vis_output region of d_out (poisoned 0xAA before every call)
    k_zero<<<(1572864 + 255) / 256, 256, 0, stream>>>(vis, 1572864);

    // mean over T
    k_mean_partial<<<B_ * 64, 256, 0, stream>>>(inputs, part);
    k_mean_final<<<48, 256, 0, stream>>>(part, x);

    // ret_x path: relu(x@d1w.T+d1b)@d2w.T+d2b
    k_gemm_wt<1><<<dim3(24, 1), 256, 0, stream>>>(x, D_, d1w, D_, d1b, h1d, D_, B_, D_, D_);
    k_gemm_wt<0><<<dim3(24, 1), 256, 0, stream>>>(h1d, D_, d2w, D_, d2b, retx, D_, B_, D_, D_);

    // xt path
    k_gemm_wt<1><<<dim3(24, 1), 256, 0, stream>>>(x, D_, t1w, D_, t1b, h1t, D_, B_, D_, D_);
    k_gemm_wt<0><<<dim3(24, 1), 256, 0, stream>>>(h1t, D_, t2w, D_, t2b, xt, D_, B_, D_, D_);

    // fm path: relu(features[:,1:]@m1w.T+m1b)@m2w.T+m2b, fm written into right
    // half of hxcat (ldc=1536) to fuse the concat
    k_gemm_wt<1><<<dim3(24, 32), 256, 0, stream>>>(features + 1, 1 + DDETR, m1w, DDETR, m1b,
                                                   fm1, D_, NBOX, D_, DDETR);
    k_gemm_wt<0><<<dim3(24, 32), 256, 0, stream>>>(fm1, D_, m2w, D_, m2b,
                                                   hxcat + D_, 2 * D_, NBOX, D_, D_);

    // left half of concat: xt[img]
    k_gather_xt<<<NBOX, 256, 0, stream>>>(xt, bboxes, hxcat);

    // h = hxcat @ pw.T + pb
    k_gemm_wt<0><<<dim3(24, 32), 256, 0, stream>>>(hxcat, 2 * D_, pw, 2 * D_, pb,
                                                   h, D_, NBOX, D_, 2 * D_);

    // counts / pos / att_mask, then scatter
    k_meta<<<1, 256, 0, stream>>>(bboxes, pos, att);
    k_scatter<<<NBOX, 256, 0, stream>>>(h, bboxes, pos, vis);
}

// Round 2
// 490.766 us; speedup vs baseline: 1.9884x; 1.9884x over previous
//
#include <hip/hip_runtime.h>

#define B_ 16
#define T_ 4096
#define D_ 768
#define NBOX 1024
#define MAXBB 128
#define DDETR 256

// ================= mean over T (two-stage, float4, deterministic) ==========
// grid: B_*64 blocks, 192 threads. Block (b,c) sums 64 t-rows of batch b.
__global__ __launch_bounds__(192) void k_mean_partial(const float4* __restrict__ in4,
                                                      float4* __restrict__ part4) {
    int blk = blockIdx.x;
    int b = blk >> 6;
    int c = blk & 63;
    int t = threadIdx.x;              // f4 column 0..191
    const float4* base = in4 + (size_t)b * (T_ * D_ / 4) + (size_t)c * (64 * D_ / 4);
    float4 s = {0.f, 0.f, 0.f, 0.f};
    #pragma unroll 4
    for (int r = 0; r < 64; ++r) {
        float4 v = base[(size_t)r * 192 + t];
        s.x += v.x; s.y += v.y; s.z += v.z; s.w += v.w;
    }
    part4[(size_t)blk * 192 + t] = s;
}

__global__ __launch_bounds__(256) void k_mean_final(const float4* __restrict__ part4,
                                                    float4* __restrict__ x4) {
    int idx = blockIdx.x * 256 + threadIdx.x;     // 16*192 = 3072
    if (idx >= B_ * 192) return;
    int b = idx / 192;
    int t = idx - b * 192;
    float4 s = {0.f, 0.f, 0.f, 0.f};
    for (int c = 0; c < 64; ++c) {
        float4 v = part4[(size_t)(b * 64 + c) * 192 + t];
        s.x += v.x; s.y += v.y; s.z += v.z; s.w += v.w;
    }
    const float inv = 1.0f / T_;
    s.x *= inv; s.y *= inv; s.z *= inv; s.w *= inv;
    x4[idx] = s;
}

// ================= big GEMM: P[z] = A[:, kslice] @ W[:, kslice]^T ==========
// 64x64 tile, BK=16, 256 threads, 4x4 micro-tile, float4 LDS reads,
// prefetch across barrier. M%64==0, N%64==0, K%16==0, lenk%16==0 assumed.
// VECA=0 -> scalar A loads (for misaligned/odd-lda A).
template<int VECA>
__global__ __launch_bounds__(256) void k_gemm64(const float* __restrict__ A, int lda,
                                                const float* __restrict__ W, int ldw,
                                                float* __restrict__ P, int mn,
                                                int N, int K, int lenk) {
    __shared__ float As[16][72];
    __shared__ float Ws[16][72];
    int tid = threadIdx.x;
    int tx = tid & 15, ty = tid >> 4;
    int n0 = blockIdx.x * 64, m0 = blockIdx.y * 64;
    int kb = blockIdx.z * lenk;
    int ke = min(K, kb + lenk);
    int r = tid >> 2, kc = (tid & 3) * 4;

    const float* Ap = A + (size_t)(m0 + r) * lda + kb + kc;
    const float* Wp = W + (size_t)(n0 + r) * ldw + kb + kc;

    float4 acc0 = {0,0,0,0}, acc1 = {0,0,0,0}, acc2 = {0,0,0,0}, acc3 = {0,0,0,0};
    float a0=0,a1=0,a2=0,a3=0, w0=0,w1=0,w2=0,w3=0;

    if (kb < ke) {
        if (VECA) { float4 v = *(const float4*)Ap; a0=v.x; a1=v.y; a2=v.z; a3=v.w; }
        else      { a0=Ap[0]; a1=Ap[1]; a2=Ap[2]; a3=Ap[3]; }
        { float4 v = *(const float4*)Wp; w0=v.x; w1=v.y; w2=v.z; w3=v.w; }

        for (int k0 = kb; k0 < ke; k0 += 16) {
            __syncthreads();
            As[kc+0][r]=a0; As[kc+1][r]=a1; As[kc+2][r]=a2; As[kc+3][r]=a3;
            Ws[kc+0][r]=w0; Ws[kc+1][r]=w1; Ws[kc+2][r]=w2; Ws[kc+3][r]=w3;
            __syncthreads();
            Ap += 16; Wp += 16;
            if (k0 + 16 < ke) {
                if (VECA) { float4 v = *(const float4*)Ap; a0=v.x; a1=v.y; a2=v.z; a3=v.w; }
                else      { a0=Ap[0]; a1=Ap[1]; a2=Ap[2]; a3=Ap[3]; }
                { float4 v = *(const float4*)Wp; w0=v.x; w1=v.y; w2=v.z; w3=v.w; }
            }
            #pragma unroll
            for (int kk = 0; kk < 16; ++kk) {
                float4 av = *(const float4*)&As[kk][ty * 4];
                float4 wv = *(const float4*)&Ws[kk][tx * 4];
                acc0.x += av.x * wv.x; acc0.y += av.x * wv.y; acc0.z += av.x * wv.z; acc0.w += av.x * wv.w;
                acc1.x += av.y * wv.x; acc1.y += av.y * wv.y; acc1.z += av.y * wv.z; acc1.w += av.y * wv.w;
                acc2.x += av.z * wv.x; acc2.y += av.z * wv.y; acc2.z += av.z * wv.z; acc2.w += av.z * wv.w;
                acc3.x += av.w * wv.x; acc3.y += av.w * wv.y; acc3.z += av.w * wv.z; acc3.w += av.w * wv.w;
            }
        }
    }
    float* p = P + (size_t)blockIdx.z * mn + (size_t)(m0 + ty * 4) * N + n0 + tx * 4;
    *(float4*)p = acc0; p += N;
    *(float4*)p = acc1; p += N;
    *(float4*)p = acc2; p += N;
    *(float4*)p = acc3;
}

// ============ epilogue: C = act(sum_z P[z] + bias), with output ldc ========
template<int RELU>
__global__ __launch_bounds__(256) void k_epilogue(const float* __restrict__ P, int mn, int KS,
                                                  const float* __restrict__ bias,
                                                  float* __restrict__ C, int N, int ldc) {
    int idx = blockIdx.x * 256 + threadIdx.x;   // f4 index over M*N/4
    int nf4 = N >> 2;
    int m = idx / nf4;
    int c4 = idx - m * nf4;
    size_t off = (size_t)m * N + c4 * 4;
    float4 s = *(const float4*)&P[off];
    for (int z = 1; z < KS; ++z) {
        float4 t = *(const float4*)&P[(size_t)z * mn + off];
        s.x += t.x; s.y += t.y; s.z += t.z; s.w += t.w;
    }
    float4 b = *(const float4*)&bias[c4 * 4];
    s.x += b.x; s.y += b.y; s.z += b.z; s.w += b.w;
    if (RELU) {
        s.x = fmaxf(s.x, 0.f); s.y = fmaxf(s.y, 0.f);
        s.z = fmaxf(s.z, 0.f); s.w = fmaxf(s.w, 0.f);
    }
    *(float4*)&C[(size_t)m * ldc + c4 * 4] = s;
}

// ================= small-M GEMM (M=16): C = act(A@W^T + bias) ==============
// 16x64 tile, BK=32, 256 threads, 4 rows/thread.
__device__ __forceinline__ void smallM_gemm(const float* __restrict__ A, int lda,
                                            const float* __restrict__ W, int ldw,
                                            const float* __restrict__ bias,
                                            float* __restrict__ C, int ldc,
                                            int K, int relu, int n0) {
    __shared__ float xs[32][17];
    __shared__ float ws_[32][68];
    int tid = threadIdx.x;
    int tx = tid & 63, ty = tid >> 6;
    float acc[4] = {0.f, 0.f, 0.f, 0.f};
    for (int k0 = 0; k0 < K; k0 += 32) {
        __syncthreads();
        #pragma unroll
        for (int i = 0; i < 2; ++i) {
            int e = tid + i * 256;
            int rr = e >> 5, kk = e & 31;
            xs[kk][rr] = A[(size_t)rr * lda + k0 + kk];
        }
        #pragma unroll
        for (int i = 0; i < 2; ++i) {
            int f = tid + i * 256;
            int row = f >> 3, kcc = (f & 7) * 4;
            float4 wv = *(const float4*)(W + (size_t)(n0 + row) * ldw + k0 + kcc);
            ws_[kcc + 0][row] = wv.x; ws_[kcc + 1][row] = wv.y;
            ws_[kcc + 2][row] = wv.z; ws_[kcc + 3][row] = wv.w;
        }
        __syncthreads();
        #pragma unroll
        for (int kk = 0; kk < 32; ++kk) {
            float wv = ws_[kk][tx];
            acc[0] += xs[kk][ty +  0] * wv;
            acc[1] += xs[kk][ty +  4] * wv;
            acc[2] += xs[kk][ty +  8] * wv;
            acc[3] += xs[kk][ty + 12] * wv;
        }
    }
    float bv = bias[n0 + tx];
    #pragma unroll
    for (int i = 0; i < 4; ++i) {
        float v = acc[i] + bv;
        if (relu) v = fmaxf(v, 0.f);
        C[(size_t)(ty + 4 * i) * ldc + n0 + tx] = v;
    }
}

__global__ __launch_bounds__(256) void k_small_l1(const float* __restrict__ x,
                                                  const float* __restrict__ d1w, const float* __restrict__ d1b,
                                                  const float* __restrict__ t1w, const float* __restrict__ t1b,
                                                  float* __restrict__ xcat1) {
    int n0 = blockIdx.x * 64;
    if (blockIdx.y == 0) smallM_gemm(x, D_, d1w, D_, d1b, xcat1,       2 * D_, D_, 1, n0);
    else                 smallM_gemm(x, D_, t1w, D_, t1b, xcat1 + D_,  2 * D_, D_, 1, n0);
}

__global__ __launch_bounds__(256) void k_small_l2(const float* __restrict__ xcat1,
                                                  const float* __restrict__ d2w, const float* __restrict__ d2b,
                                                  const float* __restrict__ t2w, const float* __restrict__ t2b,
                                                  float* __restrict__ retx, float* __restrict__ xt) {
    int n0 = blockIdx.x * 64;
    if (blockIdx.y == 0) smallM_gemm(xcat1,      2 * D_, d2w, D_, d2b, retx, D_, D_, 0, n0);
    else                 smallM_gemm(xcat1 + D_, 2 * D_, t2w, D_, t2b, xt,   D_, D_, 0, n0);
}

// ================= gather xt[img] into left half of hxcat ==================
__global__ __launch_bounds__(256) void k_gather(const float* __restrict__ xt,
                                                const int* __restrict__ bboxes,
                                                float* __restrict__ hxcat) {
    int idx = blockIdx.x * 256 + threadIdx.x;   // 1024*192
    int i = idx / 192, d = idx - i * 192;
    int img = bboxes[i * 5];
    *(float4*)&hxcat[(size_t)i * (2 * D_) + d * 4] =
        *(const float4*)&xt[(size_t)img * D_ + d * 4];
}

// ================= counts / offsets / att_mask =============================
__global__ __launch_bounds__(256) void k_meta(const int* __restrict__ bboxes,
                                              int* __restrict__ cnt_g, int* __restrict__ off_g,
                                              float* __restrict__ att) {
    __shared__ int cnt[B_];
    __shared__ int off[B_];
    int tid = threadIdx.x;
    if (tid < B_) cnt[tid] = 0;
    __syncthreads();
    for (int i = tid; i < NBOX; i += 256) atomicAdd(&cnt[bboxes[i * 5]], 1);
    __syncthreads();
    if (tid == 0) {
        int acc = 0;
        for (int b = 0; b < B_; ++b) { off[b] = acc; acc += cnt[b]; }
    }
    __syncthreads();
    if (tid < B_) { cnt_g[tid] = cnt[tid]; off_g[tid] = off[tid]; }
    for (int j = tid; j < B_ * MAXBB; j += 256) {
        int b = j >> 7, p = j & 127;
        att[j] = (p < cnt[b]) ? 1.0f : 0.0f;
    }
}

// ======= vis: every slot written exactly once (row of h or zeros) ==========
__global__ __launch_bounds__(256) void k_vis(const float* __restrict__ h,
                                             const int* __restrict__ cnt,
                                             const int* __restrict__ off,
                                             float* __restrict__ vis) {
    int idx = blockIdx.x * 256 + threadIdx.x;   // 16*128*192
    int slot = idx / 192, d = idx - slot * 192;
    int b = slot >> 7, p = slot & 127;
    float4 v = {0.f, 0.f, 0.f, 0.f};
    if (p < cnt[b]) v = *(const float4*)&h[(size_t)(off[b] + p) * D_ + d * 4];
    *(float4*)&vis[(size_t)slot * D_ + d * 4] = v;
}

extern "C" void kernel_launch(void* const* d_in, const int* in_sizes, int n_in,
                              void* d_out, int out_size, void* d_ws, size_t ws_size,
                              hipStream_t stream) {
    const float* inputs   = (const float*)d_in[0];
    const int*   bboxes   = (const int*)d_in[1];
    const float* features = (const float*)d_in[2];
    const float* t1w = (const float*)d_in[3];
    const float* t1b = (const float*)d_in[4];
    const float* t2w = (const float*)d_in[5];
    const float* t2b = (const float*)d_in[6];
    const float* d1w = (const float*)d_in[7];
    const float* d1b = (const float*)d_in[8];
    const float* d2w = (const float*)d_in[9];
    const float* d2b = (const float*)d_in[10];
    const float* m1w = (const float*)d_in[11];
    const float* m1b = (const float*)d_in[12];
    const float* m2w = (const float*)d_in[13];
    const float* m2b = (const float*)d_in[14];
    const float* pw  = (const float*)d_in[15];
    const float* pb  = (const float*)d_in[16];

    float* out  = (float*)d_out;
    float* vis  = out;                       // 16*128*768 = 1572864
    float* att  = out + 1572864;             // 2048
    float* retx = out + 1574912;             // 12288

    const int MN = NBOX * D_;                // 786432
    float* ws    = (float*)d_ws;
    float* part  = ws;                        // 786432 (reused as fm1 buffer)
    float* fm1b  = ws;                        // alias, live after mean done
    float* x     = part + 786432;             // 12288
    float* xcat1 = x + 12288;                 // 24576
    float* xt    = xcat1 + 24576;             // 12288
    float* hxcat = xt + 12288;                // 1572864
    float* h     = hxcat + 1572864;           // 786432
    int*   cnt   = (int*)(h + 786432);        // 16
    int*   off   = cnt + 16;                  // 16
    float* P     = (float*)(off + 48);        // split-K slabs, 16B-ish aligned

    // runtime split-K: fit slabs in remaining workspace
    size_t used_floats = (size_t)(P - ws);
    size_t avail = ws_size / 4 > used_floats ? ws_size / 4 - used_floats : 0;
    int KS = (avail >= (size_t)3 * MN) ? 3 : (avail >= (size_t)2 * MN) ? 2 : 1;

    auto lenk_for = [KS](int K) { return (((K + KS - 1) / KS) + 15) & ~15; };

    // meta (independent)
    k_meta<<<1, 256, 0, stream>>>(bboxes, cnt, off, att);

    // mean over T
    k_mean_partial<<<B_ * 64, 192, 0, stream>>>((const float4*)inputs, (float4*)part);
    k_mean_final<<<12, 256, 0, stream>>>((const float4*)part, (float4*)x);

    // tiny M=16 chains (d-path and t-path fused per layer)
    k_small_l1<<<dim3(12, 2), 256, 0, stream>>>(x, d1w, d1b, t1w, t1b, xcat1);
    k_small_l2<<<dim3(12, 2), 256, 0, stream>>>(xcat1, d2w, d2b, t2w, t2b, retx, xt);

    // fm1 = relu(features[:,1:] @ m1w^T + m1b)  (A misaligned: VECA=0)
    k_gemm64<0><<<dim3(12, 16, KS), 256, 0, stream>>>(features + 1, 1 + DDETR, m1w, DDETR,
                                                      P, MN, D_, DDETR, lenk_for(DDETR));
    k_epilogue<1><<<768, 256, 0, stream>>>(P, MN, KS, m1b, fm1b, D_, D_);

    // fm = fm1 @ m2w^T + m2b  -> right half of hxcat
    k_gemm64<1><<<dim3(12, 16, KS), 256, 0, stream>>>(fm1b, D_, m2w, D_,
                                                      P, MN, D_, D_, lenk_for(D_));
    k_epilogue<0><<<768, 256, 0, stream>>>(P, MN, KS, m2b, hxcat + D_, D_, 2 * D_);

    // left half of hxcat: xt[img]
    k_gather<<<768, 256, 0, stream>>>(xt, bboxes, hxcat);

    // h = hxcat @ pw^T + pb
    k_gemm64<1><<<dim3(12, 16, KS), 256, 0, stream>>>(hxcat, 2 * D_, pw, 2 * D_,
                                                      P, MN, D_, 2 * D_, lenk_for(2 * D_));
    k_epilogue<0><<<768, 256, 0, stream>>>(P, MN, KS, pb, h, D_, D_);

    // vis_output: every slot written (h row or zeros)
    k_vis<<<1536, 256, 0, stream>>>(h, cnt, off, vis);
}

// Round 3
// 427.223 us; speedup vs baseline: 2.2841x; 1.1487x over previous
//
#include <hip/hip_runtime.h>

#define B_ 16
#define T_ 4096
#define D_ 768
#define NBOX 1024
#define MAXBB 128
#define DDETR 256

typedef unsigned short u16;
typedef short bf16x8 __attribute__((ext_vector_type(8)));
typedef float f32x4 __attribute__((ext_vector_type(4)));

// round-to-nearest-even fp32 -> bf16 split: f ~= hi + lo (both bf16)
__device__ __forceinline__ void split_bf(float f, u16& h, u16& l) {
    unsigned u = __builtin_bit_cast(unsigned, f);
    unsigned r = u + 0x7fffu + ((u >> 16) & 1u);
    u16 hb = (u16)(r >> 16);
    float hf = __builtin_bit_cast(float, (unsigned)hb << 16);
    float lf = f - hf;
    unsigned ul = __builtin_bit_cast(unsigned, lf);
    unsigned rl = ul + 0x7fffu + ((ul >> 16) & 1u);
    h = hb; l = (u16)(rl >> 16);
}

// ================= mean over T (two-stage, float4, deterministic) ==========
__global__ __launch_bounds__(192) void k_mean_partial(const float4* __restrict__ in4,
                                                      float4* __restrict__ part4) {
    int blk = blockIdx.x;
    int b = blk >> 6, c = blk & 63;
    int t = threadIdx.x;
    const float4* base = in4 + (size_t)b * (T_ * D_ / 4) + (size_t)c * (64 * D_ / 4);
    float4 s = {0.f, 0.f, 0.f, 0.f};
    #pragma unroll 4
    for (int r = 0; r < 64; ++r) {
        float4 v = base[(size_t)r * 192 + t];
        s.x += v.x; s.y += v.y; s.z += v.z; s.w += v.w;
    }
    part4[(size_t)blk * 192 + t] = s;
}

// final reduce + pack x into tiled bf16 hi/lo [kc=96][r=16][8]
__global__ __launch_bounds__(96) void k_mean_final_pack(const float* __restrict__ part,
                                                        u16* __restrict__ xph, u16* __restrict__ xpl) {
    int b = blockIdx.x;          // 0..15  (row of x)
    int kc = threadIdx.x;        // 0..95
    f32x4 s0 = {0,0,0,0}, s1 = {0,0,0,0};
    for (int c = 0; c < 64; ++c) {
        const float* p = part + ((size_t)(b * 64 + c)) * D_ + kc * 8;
        s0 += *(const f32x4*)p;
        s1 += *(const f32x4*)(p + 4);
    }
    const float inv = 1.0f / T_;
    bf16x8 hv, lv;
    #pragma unroll
    for (int j = 0; j < 4; ++j) {
        u16 h, l;
        split_bf(s0[j] * inv, h, l); hv[j] = (short)h; lv[j] = (short)l;
        split_bf(s1[j] * inv, h, l); hv[4 + j] = (short)h; lv[4 + j] = (short)l;
    }
    size_t off = ((size_t)kc * 16 + b) * 8;
    *(bf16x8*)(xph + off) = hv;
    *(bf16x8*)(xpl + off) = lv;
}

// ================= weight pack: fp32 (N,K) row-major -> tiled hi/lo ========
struct WDesc { const float* src; u16* hi; u16* lo; int N; int K; };
struct WPack7 { WDesc d[7]; };

__global__ __launch_bounds__(256) void k_pack_w(WPack7 ws) {
    WDesc d = ws.d[blockIdx.y];
    int idx = blockIdx.x * 256 + threadIdx.x;
    int Kc = d.K >> 3;
    int total = d.N * Kc;
    if (idx >= total) return;
    int n = idx / Kc, kc = idx - n * Kc;
    const float* s = d.src + (size_t)n * d.K + kc * 8;
    f32x4 v0 = *(const f32x4*)s, v1 = *(const f32x4*)(s + 4);
    bf16x8 hv, lv;
    #pragma unroll
    for (int j = 0; j < 4; ++j) {
        u16 h, l;
        split_bf(v0[j], h, l); hv[j] = (short)h; lv[j] = (short)l;
        split_bf(v1[j], h, l); hv[4 + j] = (short)h; lv[4 + j] = (short)l;
    }
    size_t off = ((size_t)(n >> 4) * Kc + kc) * 128 + (n & 15) * 8;
    *(bf16x8*)(d.hi + off) = hv;
    *(bf16x8*)(d.lo + off) = lv;
}

// features[:,1:] (misaligned, stride 257) -> tiled hi/lo, Kc=32
__global__ __launch_bounds__(256) void k_pack_feat(const float* __restrict__ feat,
                                                   u16* __restrict__ fh, u16* __restrict__ fl) {
    int idx = blockIdx.x * 256 + threadIdx.x;      // < 1024*32
    if (idx >= NBOX * 32) return;
    int i = idx >> 5, kc = idx & 31;
    const float* s = feat + (size_t)i * 257 + 1 + kc * 8;
    bf16x8 hv, lv;
    #pragma unroll
    for (int j = 0; j < 8; ++j) {
        u16 h, l;
        split_bf(s[j], h, l); hv[j] = (short)h; lv[j] = (short)l;
    }
    size_t off = ((size_t)(i >> 4) * 32 + kc) * 128 + (i & 15) * 8;
    *(bf16x8*)(fh + off) = hv;
    *(bf16x8*)(fl + off) = lv;
}

// ================= big MFMA GEMM: P[z] = A_t . W_t^T (term/ks by z) ========
// A,W in tiled layout [t16][kc][16][8]. M=1024, N=768 fixed. 128x128 block,
// 4 waves of 64x64, direct-global fragment loads (no LDS).
__global__ __launch_bounds__(256) void k_mfma(const u16* __restrict__ Ahi, const u16* __restrict__ Alo,
                                              const u16* __restrict__ Whi, const u16* __restrict__ Wlo,
                                              float* __restrict__ P, int Kc, int kcLen, int nks) {
    int z = blockIdx.z;
    int term = z / nks, ks = z - term * nks;
    const u16* A = (term == 2) ? Alo : Ahi;
    const u16* W = (term == 1) ? Wlo : Whi;
    int lane = threadIdx.x & 63, w = threadIdx.x >> 6;
    int wm = w >> 1, wn = w & 1;
    int mt0 = blockIdx.y * 8 + wm * 4;    // 16-row tile idx
    int nt0 = blockIdx.x * 8 + wn * 4;
    int kc0 = ks * kcLen;
    int nk = kcLen >> 2;                   // K=32 steps

    const u16* Ap = A + ((size_t)mt0 * Kc + kc0) * 128 + lane * 8;
    const u16* Wp = W + ((size_t)nt0 * Kc + kc0) * 128 + lane * 8;
    size_t astr = (size_t)Kc * 128;

    bf16x8 a[4], b[4];
    #pragma unroll
    for (int i = 0; i < 4; ++i) {
        a[i] = *(const bf16x8*)(Ap + i * astr);
        b[i] = *(const bf16x8*)(Wp + i * astr);
    }
    f32x4 acc[16];
    #pragma unroll
    for (int i = 0; i < 16; ++i) acc[i] = (f32x4){0.f, 0.f, 0.f, 0.f};

    for (int k = 0; k < nk; ++k) {
        bf16x8 an[4], bn[4];
        if (k + 1 < nk) {
            #pragma unroll
            for (int i = 0; i < 4; ++i) {
                an[i] = *(const bf16x8*)(Ap + i * astr + (size_t)(k + 1) * 512);
                bn[i] = *(const bf16x8*)(Wp + i * astr + (size_t)(k + 1) * 512);
            }
        }
        #pragma unroll
        for (int i = 0; i < 4; ++i)
            #pragma unroll
            for (int j = 0; j < 4; ++j)
                acc[i * 4 + j] = __builtin_amdgcn_mfma_f32_16x16x32_bf16(a[i], b[j], acc[i * 4 + j], 0, 0, 0);
        #pragma unroll
        for (int i = 0; i < 4; ++i) { a[i] = an[i]; b[i] = bn[i]; }
    }

    float* Pz = P + (size_t)z * (1024 * 768);
    int rb = (lane >> 4) * 4, cb = lane & 15;
    #pragma unroll
    for (int i = 0; i < 4; ++i)
        #pragma unroll
        for (int j = 0; j < 4; ++j) {
            int row = (mt0 + i) * 16 + rb;
            int col = (nt0 + j) * 16 + cb;
            float* p = Pz + (size_t)row * 768 + col;
            f32x4 v = acc[i * 4 + j];
            #pragma unroll
            for (int r = 0; r < 4; ++r) p[(size_t)r * 768] = v[r];
        }
}

// ============ big epilogue -> packed bf16 (next GEMM's A operand) ==========
template<int RELU>
__global__ __launch_bounds__(256) void k_epi_pack(const float* __restrict__ P, int NS,
                                                  const float* __restrict__ bias,
                                                  u16* __restrict__ dhi, u16* __restrict__ dlo,
                                                  int KcDst, int kcOff) {
    int idx = blockIdx.x * 256 + threadIdx.x;   // < 1024*96
    int m = idx / 96, kc = idx - m * 96;
    const float* p0 = P + (size_t)m * 768 + kc * 8;
    f32x4 s0 = *(const f32x4*)p0, s1 = *(const f32x4*)(p0 + 4);
    for (int z = 1; z < NS; ++z) {
        const float* p = p0 + (size_t)z * (1024 * 768);
        s0 += *(const f32x4*)p; s1 += *(const f32x4*)(p + 4);
    }
    s0 += *(const f32x4*)(bias + kc * 8);
    s1 += *(const f32x4*)(bias + kc * 8 + 4);
    bf16x8 hv, lv;
    #pragma unroll
    for (int j = 0; j < 4; ++j) {
        float v0 = RELU ? fmaxf(s0[j], 0.f) : s0[j];
        float v1 = RELU ? fmaxf(s1[j], 0.f) : s1[j];
        u16 h, l;
        split_bf(v0, h, l); hv[j] = (short)h; lv[j] = (short)l;
        split_bf(v1, h, l); hv[4 + j] = (short)h; lv[4 + j] = (short)l;
    }
    size_t off = ((size_t)(m >> 4) * KcDst + kcOff + kc) * 128 + (m & 15) * 8;
    *(bf16x8*)(dhi + off) = hv;
    *(bf16x8*)(dlo + off) = lv;
}

// ============ big epilogue -> fp32 row-major (h) ===========================
__global__ __launch_bounds__(256) void k_epi_f32(const float* __restrict__ P, int NS,
                                                 const float* __restrict__ bias,
                                                 float* __restrict__ C) {
    int idx = blockIdx.x * 256 + threadIdx.x;   // < 1024*192
    int m = idx / 192, c4 = idx - m * 192;
    size_t off = (size_t)m * 768 + c4 * 4;
    f32x4 s = *(const f32x4*)(P + off);
    for (int z = 1; z < NS; ++z) s += *(const f32x4*)(P + (size_t)z * (1024 * 768) + off);
    s += *(const f32x4*)(bias + c4 * 4);
    *(f32x4*)(C + off) = s;
}

// ================= small-M (M=16) MFMA GEMM, combined N=1536 [d|t] =========
// grid (6, 12): x = n-block (16 tiles), y = z (term*4+ks). Kc=96, slice 24.
__global__ __launch_bounds__(256) void k_small(const u16* __restrict__ A0h, const u16* __restrict__ A0l,
                                               const u16* __restrict__ A1h, const u16* __restrict__ A1l,
                                               const u16* __restrict__ W0h, const u16* __restrict__ W0l,
                                               const u16* __restrict__ W1h, const u16* __restrict__ W1l,
                                               float* __restrict__ Ps) {
    int z = blockIdx.y;
    int term = z >> 2, ks = z & 3;
    int lane = threadIdx.x & 63, w = threadIdx.x >> 6;
    int nt0 = blockIdx.x * 16 + w * 4;           // global n-tile 0..95
    int path = nt0 >= 48;
    int ntp = nt0 - path * 48;
    const u16* Ah = path ? A1h : A0h;
    const u16* Al = path ? A1l : A0l;
    const u16* Wh = path ? W1h : W0h;
    const u16* Wl = path ? W1l : W0l;
    const u16* A = (term == 2) ? Al : Ah;
    const u16* W = (term == 1) ? Wl : Wh;
    int kc0 = ks * 24;

    const u16* Ap = A + (size_t)kc0 * 128 + lane * 8;
    const u16* Wp = W + ((size_t)ntp * 96 + kc0) * 128 + lane * 8;

    f32x4 acc[4];
    #pragma unroll
    for (int i = 0; i < 4; ++i) acc[i] = (f32x4){0.f, 0.f, 0.f, 0.f};

    #pragma unroll
    for (int k = 0; k < 6; ++k) {
        bf16x8 a = *(const bf16x8*)(Ap + (size_t)k * 512);
        bf16x8 b[4];
        #pragma unroll
        for (int j = 0; j < 4; ++j)
            b[j] = *(const bf16x8*)(Wp + (size_t)j * 96 * 128 + (size_t)k * 512);
        #pragma unroll
        for (int j = 0; j < 4; ++j)
            acc[j] = __builtin_amdgcn_mfma_f32_16x16x32_bf16(a, b[j], acc[j], 0, 0, 0);
    }

    float* Pz = Ps + (size_t)z * (16 * 1536);
    int rb = (lane >> 4) * 4, cb = lane & 15;
    #pragma unroll
    for (int j = 0; j < 4; ++j) {
        int col = (nt0 + j) * 16 + cb;
        float* p = Pz + (size_t)rb * 1536 + col;
        f32x4 v = acc[j];
        #pragma unroll
        for (int r = 0; r < 4; ++r) p[(size_t)r * 1536] = v[r];
    }
}

// small epilogue 1: relu -> xc1 packed hi/lo [path][kc=96][16][8]
__global__ __launch_bounds__(256) void k_sepi1(const float* __restrict__ Ps,
                                               const float* __restrict__ d1b, const float* __restrict__ t1b,
                                               u16* __restrict__ xh, u16* __restrict__ xl) {
    int idx = blockIdx.x * 256 + threadIdx.x;   // < 16*192
    int r = idx / 192, cc = idx - r * 192;
    size_t base = (size_t)r * 1536 + cc * 8;
    f32x4 s0 = {0,0,0,0}, s1 = {0,0,0,0};
    for (int z = 0; z < 12; ++z) {
        const float* p = Ps + (size_t)z * (16 * 1536) + base;
        s0 += *(const f32x4*)p; s1 += *(const f32x4*)(p + 4);
    }
    int path = cc >= 96;
    int ccp = cc - path * 96;
    const float* bias = (path ? t1b : d1b) + ccp * 8;
    s0 += *(const f32x4*)bias;
    s1 += *(const f32x4*)(bias + 4);
    bf16x8 hv, lv;
    #pragma unroll
    for (int j = 0; j < 4; ++j) {
        u16 h, l;
        split_bf(fmaxf(s0[j], 0.f), h, l); hv[j] = (short)h; lv[j] = (short)l;
        split_bf(fmaxf(s1[j], 0.f), h, l); hv[4 + j] = (short)h; lv[4 + j] = (short)l;
    }
    size_t off = (size_t)path * 12288 + (size_t)ccp * 128 + r * 8;
    *(bf16x8*)(xh + off) = hv;
    *(bf16x8*)(xl + off) = lv;
}

// small epilogue 2: d-path -> retx fp32, t-path -> xt packed hi/lo
__global__ __launch_bounds__(256) void k_sepi2(const float* __restrict__ Ps,
                                               const float* __restrict__ d2b, const float* __restrict__ t2b,
                                               float* __restrict__ retx,
                                               u16* __restrict__ xth, u16* __restrict__ xtl) {
    int idx = blockIdx.x * 256 + threadIdx.x;   // < 16*192
    int r = idx / 192, cc = idx - r * 192;
    size_t base = (size_t)r * 1536 + cc * 8;
    f32x4 s0 = {0,0,0,0}, s1 = {0,0,0,0};
    for (int z = 0; z < 12; ++z) {
        const float* p = Ps + (size_t)z * (16 * 1536) + base;
        s0 += *(const f32x4*)p; s1 += *(const f32x4*)(p + 4);
    }
    int path = cc >= 96;
    int ccp = cc - path * 96;
    const float* bias = (path ? t2b : d2b) + ccp * 8;
    s0 += *(const f32x4*)bias;
    s1 += *(const f32x4*)(bias + 4);
    if (!path) {
        float* o = retx + (size_t)r * 768 + ccp * 8;
        *(f32x4*)o = s0;
        *(f32x4*)(o + 4) = s1;
    } else {
        bf16x8 hv, lv;
        #pragma unroll
        for (int j = 0; j < 4; ++j) {
            u16 h, l;
            split_bf(s0[j], h, l); hv[j] = (short)h; lv[j] = (short)l;
            split_bf(s1[j], h, l); hv[4 + j] = (short)h; lv[4 + j] = (short)l;
        }
        size_t off = (size_t)ccp * 128 + r * 8;
        *(bf16x8*)(xth + off) = hv;
        *(bf16x8*)(xtl + off) = lv;
    }
}

// gather packed xt rows into left kc-half of packed hxcat (pure 16B copies)
__global__ __launch_bounds__(256) void k_gather_pack(const u16* __restrict__ xth, const u16* __restrict__ xtl,
                                                     const int* __restrict__ bboxes,
                                                     u16* __restrict__ hxh, u16* __restrict__ hxl) {
    int idx = blockIdx.x * 256 + threadIdx.x;   // < 1024*96
    int i = idx / 96, kc = idx - i * 96;
    int img = bboxes[i * 5];
    size_t soff = ((size_t)kc * 16 + img) * 8;
    size_t doff = ((size_t)(i >> 4) * 192 + kc) * 128 + (i & 15) * 8;
    *(bf16x8*)(hxh + doff) = *(const bf16x8*)(xth + soff);
    *(bf16x8*)(hxl + doff) = *(const bf16x8*)(xtl + soff);
}

// ================= counts / offsets / att_mask =============================
__global__ __launch_bounds__(256) void k_meta(const int* __restrict__ bboxes,
                                              int* __restrict__ cnt_g, int* __restrict__ off_g,
                                              float* __restrict__ att) {
    __shared__ int cnt[B_];
    __shared__ int off[B_];
    int tid = threadIdx.x;
    if (tid < B_) cnt[tid] = 0;
    __syncthreads();
    for (int i = tid; i < NBOX; i += 256) atomicAdd(&cnt[bboxes[i * 5]], 1);
    __syncthreads();
    if (tid == 0) {
        int acc = 0;
        for (int b = 0; b < B_; ++b) { off[b] = acc; acc += cnt[b]; }
    }
    __syncthreads();
    if (tid < B_) { cnt_g[tid] = cnt[tid]; off_g[tid] = off[tid]; }
    for (int j = tid; j < B_ * MAXBB; j += 256) {
        int b = j >> 7, p = j & 127;
        att[j] = (p < cnt[b]) ? 1.0f : 0.0f;
    }
}

// ======= vis: every slot written exactly once (row of h or zeros) ==========
__global__ __launch_bounds__(256) void k_vis(const float* __restrict__ h,
                                             const int* __restrict__ cnt,
                                             const int* __restrict__ off,
                                             float* __restrict__ vis) {
    int idx = blockIdx.x * 256 + threadIdx.x;   // 16*128*192
    int slot = idx / 192, d = idx - slot * 192;
    int b = slot >> 7, p = slot & 127;
    float4 v = {0.f, 0.f, 0.f, 0.f};
    if (p < cnt[b]) v = *(const float4*)&h[(size_t)(off[b] + p) * D_ + d * 4];
    *(float4*)&vis[(size_t)slot * D_ + d * 4] = v;
}

extern "C" void kernel_launch(void* const* d_in, const int* in_sizes, int n_in,
                              void* d_out, int out_size, void* d_ws, size_t ws_size,
                              hipStream_t stream) {
    const float* inputs   = (const float*)d_in[0];
    const int*   bboxes   = (const int*)d_in[1];
    const float* features = (const float*)d_in[2];
    const float* t1w = (const float*)d_in[3];
    const float* t1b = (const float*)d_in[4];
    const float* t2w = (const float*)d_in[5];
    const float* t2b = (const float*)d_in[6];
    const float* d1w = (const float*)d_in[7];
    const float* d1b = (const float*)d_in[8];
    const float* d2w = (const float*)d_in[9];
    const float* d2b = (const float*)d_in[10];
    const float* m1w = (const float*)d_in[11];
    const float* m1b = (const float*)d_in[12];
    const float* m2w = (const float*)d_in[13];
    const float* m2b = (const float*)d_in[14];
    const float* pw  = (const float*)d_in[15];
    const float* pb  = (const float*)d_in[16];

    float* out  = (float*)d_out;
    float* vis  = out;                       // 16*128*768
    float* att  = out + 1572864;             // 2048
    float* retx = out + 1574912;             // 12288

    // ---- workspace layout (floats) ----
    float* wsf  = (float*)d_ws;
    float* part = wsf;                        // 786432
    float* P    = wsf + 786432;               // 12 * 786432
    float* Ps   = P + 12 * 786432;            // 12 * 24576 = 294912
    float* h    = Ps + 294912;                // 786432
    int*   cnt  = (int*)(h + 786432);         // 16
    int*   off  = cnt + 16;                   // 16 (pad to 48)
    u16*   sb   = (u16*)(off + 48);           // bf16 region (16B aligned)

    u16* t1wh = sb;              u16* t1wl = t1wh + 589824;
    u16* t2wh = t1wl + 589824;   u16* t2wl = t2wh + 589824;
    u16* d1wh = t2wl + 589824;   u16* d1wl = d1wh + 589824;
    u16* d2wh = d1wl + 589824;   u16* d2wl = d2wh + 589824;
    u16* m1wh = d2wl + 589824;   u16* m1wl = m1wh + 196608;
    u16* m2wh = m1wl + 196608;   u16* m2wl = m2wh + 589824;
    u16* pwh  = m2wl + 589824;   u16* pwl  = pwh + 1179648;
    u16* feah = pwl + 1179648;   u16* feal = feah + 262144;
    u16* fm1h = feal + 262144;   u16* fm1l = fm1h + 786432;
    u16* hxh  = fm1l + 786432;   u16* hxl  = hxh + 1572864;
    u16* xph  = hxl + 1572864;   u16* xpl  = xph + 12288;
    u16* xch  = xpl + 12288;     u16* xcl  = xch + 24576;
    u16* xth  = xcl + 24576;     u16* xtl  = xth + 12288;

    // meta (independent)
    k_meta<<<1, 256, 0, stream>>>(bboxes, cnt, off, att);

    // mean over T -> packed x
    k_mean_partial<<<B_ * 64, 192, 0, stream>>>((const float4*)inputs, (float4*)part);
    k_mean_final_pack<<<16, 96, 0, stream>>>(part, xph, xpl);

    // pack all weights (one kernel, 7 matrices)
    WPack7 wp;
    wp.d[0] = {t1w, t1wh, t1wl, 768, 768};
    wp.d[1] = {t2w, t2wh, t2wl, 768, 768};
    wp.d[2] = {d1w, d1wh, d1wl, 768, 768};
    wp.d[3] = {d2w, d2wh, d2wl, 768, 768};
    wp.d[4] = {m1w, m1wh, m1wl, 768, 256};
    wp.d[5] = {m2w, m2wh, m2wl, 768, 768};
    wp.d[6] = {pw,  pwh,  pwl,  768, 1536};
    k_pack_w<<<dim3(576, 7), 256, 0, stream>>>(wp);
    k_pack_feat<<<128, 256, 0, stream>>>(features, feah, feal);

    // small chain: layer1 (x -> xc1), layer2 (xc1 -> retx | xt)
    k_small<<<dim3(6, 12), 256, 0, stream>>>(xph, xpl, xph, xpl,
                                             d1wh, d1wl, t1wh, t1wl, Ps);
    k_sepi1<<<12, 256, 0, stream>>>(Ps, d1b, t1b, xch, xcl);
    k_small<<<dim3(6, 12), 256, 0, stream>>>(xch, xcl, xch + 12288, xcl + 12288,
                                             d2wh, d2wl, t2wh, t2wl, Ps);
    k_sepi2<<<12, 256, 0, stream>>>(Ps, d2b, t2b, retx, xth, xtl);

    // gather xt[img] into left kc-half of packed hxcat
    k_gather_pack<<<384, 256, 0, stream>>>(xth, xtl, bboxes, hxh, hxl);

    // fm1 = relu(feat @ m1w^T + m1b)   (Kc=32, slice 16, 3 terms x 2)
    k_mfma<<<dim3(6, 8, 6), 256, 0, stream>>>(feah, feal, m1wh, m1wl, P, 32, 16, 2);
    k_epi_pack<1><<<384, 256, 0, stream>>>(P, 6, m1b, fm1h, fm1l, 96, 0);

    // fm = fm1 @ m2w^T + m2b -> right kc-half of packed hxcat (Kc=96, slice 24)
    k_mfma<<<dim3(6, 8, 12), 256, 0, stream>>>(fm1h, fm1l, m2wh, m2wl, P, 96, 24, 4);
    k_epi_pack<0><<<384, 256, 0, stream>>>(P, 12, m2b, hxh, hxl, 192, 96);

    // h = hxcat @ pw^T + pb  (Kc=192, slice 48)
    k_mfma<<<dim3(6, 8, 12), 256, 0, stream>>>(hxh, hxl, pwh, pwl, P, 192, 48, 4);
    k_epi_f32<<<768, 256, 0, stream>>>(P, 12, pb, h);

    // vis_output
    k_vis<<<1536, 256, 0, stream>>>(h, cnt, off, vis);
}